// Round 1
// baseline (705.089 us; speedup 1.0000x reference)
//
#include <hip/hip_runtime.h>
#include <math.h>

#define NNODES 100000
#define B 4096
#define M 256
#define G3 768
#define IN1 515
#define UB 8
#define NROUNDS 12
#define NOTDONE 0x7fffffff
#define ALPHA 0.1f

// ---------------------------------------------------------------------------
// Prep A: transpose weights into ws (coalesced GEMV loads), init flags.
// W1T[j][k] = W1[k][j]   (515 x 256)
// W2T[j][k] = W2[k][j]   (256 x 256)
// wihT[j][g] = wih[g][j] (256 x 768), whhT likewise
// ---------------------------------------------------------------------------
__global__ void tgn_prep_init(const float* __restrict__ W1, const float* __restrict__ W2,
                              const float* __restrict__ wih, const float* __restrict__ whh,
                              float* __restrict__ W1T, float* __restrict__ W2T,
                              float* __restrict__ wihT, float* __restrict__ whhT,
                              int* __restrict__ done_round, int* __restrict__ n_done)
{
    int t = blockIdx.x * 256 + threadIdx.x;
    if (t < IN1 * M) { int j = t >> 8, k = t & 255; W1T[t] = W1[k * IN1 + j]; }
    if (t < M * M)   { int j = t >> 8, k = t & 255; W2T[t] = W2[k * M + j]; }
    if (t < M * G3)  { int j = t / G3, g = t - j * G3; wihT[t] = wih[g * M + j]; whhT[t] = whh[g * M + j]; }
    if (t < B) done_round[t] = NOTDONE;
    if (t == 0) *n_done = 0;
}

// ---------------------------------------------------------------------------
// Prep B: deps. dep_s[i] = max j<i with s_j==s_i || d_j==s_i (else -1); dep_d same for d_i.
// 8 workers per step, each scans a 512-wide chunk of earlier steps from LDS.
// ---------------------------------------------------------------------------
__global__ void tgn_prep_deps(const int* __restrict__ src, const int* __restrict__ dst,
                              int* __restrict__ dep_s, int* __restrict__ dep_d)
{
    __shared__ int sL[B];
    __shared__ int dL[B];
    __shared__ int rs[256], rd[256];
    int tid = threadIdx.x;
    for (int idx = tid; idx < B; idx += 256) { sL[idx] = src[idx]; dL[idx] = dst[idx]; }
    __syncthreads();

    int gw = blockIdx.x * 256 + tid;   // 0 .. 32767
    int i = gw >> 3;                   // step
    int w = gw & 7;                    // worker
    int vs = sL[i], vd = dL[i];
    int lo = w * 512;
    int hi = (w + 1) * 512; if (hi > i) hi = i;
    int bs = -1, bd = -1;
    for (int j = hi - 1; j >= lo; --j) {
        int sj = sL[j], dj = dL[j];
        if (bs < 0 && (sj == vs || dj == vs)) bs = j;
        if (bd < 0 && (sj == vd || dj == vd)) bd = j;
        if (bs >= 0 && bd >= 0) break;
    }
    rs[tid] = bs; rd[tid] = bd;
    __syncthreads();
    if (w == 0) {
        int ms = -1, md = -1;
        #pragma unroll
        for (int q = 0; q < 8; ++q) { ms = max(ms, rs[tid + q]); md = max(md, rd[tid + q]); }
        dep_s[i] = ms; dep_d[i] = md;
    }
}

// ---------------------------------------------------------------------------
// One wavefront round. Block b owns steps [8b, 8b+8). A step runs iff undone and
// both deps finished in a STRICTLY earlier round (earlier launch => coherent).
// Thread k owns output row k for all 8 steps.
// ---------------------------------------------------------------------------
__global__ __launch_bounds__(256, 2) void tgn_round(
    int r,
    const int* __restrict__ src, const int* __restrict__ dst,
    const float* __restrict__ ef, const int* __restrict__ tsi,
    const float* __restrict__ lu0,
    const float* __restrict__ b1, const float* __restrict__ b2,
    const float* __restrict__ bih, const float* __restrict__ bhh,
    const float* __restrict__ W1T, const float* __restrict__ W2T,
    const float* __restrict__ wihT, const float* __restrict__ whhT,
    const int* __restrict__ dep_s, const int* __restrict__ dep_d,
    int* __restrict__ done_round, int* __restrict__ n_done,
    float* __restrict__ mem)
{
    __shared__ __align__(16) float ps[UB][M];
    __shared__ __align__(16) float pd[UB][M];
    __shared__ __align__(16) float h1s[UB][M];
    __shared__ __align__(16) float msg[UB][M];
    __shared__ float efs[UB][3];
    __shared__ float decS[UB], decD[UB];
    __shared__ int sA[UB], dA[UB], actA[UB];
    __shared__ int nd_sh;

    int tid = threadIdx.x;
    if (tid == 0) nd_sh = *n_done;
    __syncthreads();
    if (nd_sh >= B) return;          // uniform early exit

    if (tid < UB) {
        int i = blockIdx.x * UB + tid;
        bool ready = false;
        int a = dep_s[i], bb = dep_d[i];
        if (done_round[i] == NOTDONE) {
            ready = (a < 0 || done_round[a] < r) && (bb < 0 || done_round[bb] < r);
        }
        int s = 0, d = 0; float dcs = 0.f, dcd = 0.f, e0 = 0.f, e1 = 0.f, e2 = 0.f;
        if (ready) {
            s = src[i]; d = dst[i];
            float t = (float)tsi[i];
            float lus = (a  >= 0) ? (float)tsi[a]  : lu0[s];
            float lud = (bb >= 0) ? (float)tsi[bb] : lu0[d];
            dcs = expf(-ALPHA * fmaxf(t - lus, 0.f));
            dcd = expf(-ALPHA * fmaxf(t - lud, 0.f));
            e0 = ef[3 * i]; e1 = ef[3 * i + 1]; e2 = ef[3 * i + 2];
        }
        sA[tid] = s; dA[tid] = d; actA[tid] = ready ? 1 : 0;
        decS[tid] = dcs; decD[tid] = dcd;
        efs[tid][0] = e0; efs[tid][1] = e1; efs[tid][2] = e2;
    }
    __syncthreads();
    int anyact = 0;
    #pragma unroll
    for (int u = 0; u < UB; ++u) anyact += actA[u];
    if (anyact == 0) return;         // uniform (LDS stable after barrier)

    // decayed previous states (inactive slots: dec=0 -> zeros, node 0 read is safe)
    #pragma unroll
    for (int u = 0; u < UB; ++u) {
        ps[u][tid] = mem[(size_t)sA[u] * M + tid] * decS[u];
        pd[u][tid] = mem[(size_t)dA[u] * M + tid] * decD[u];
    }
    __syncthreads();

    // ---- GEMV1: h1 = relu(W1 @ [ps, pd, ef] + b1) ----
    {
        float acc[UB];
        float bv = b1[tid];
        #pragma unroll
        for (int u = 0; u < UB; ++u) acc[u] = bv;
        for (int j = 0; j < M; j += 4) {
            float w0 = W1T[(j + 0) * M + tid];
            float w1 = W1T[(j + 1) * M + tid];
            float w2 = W1T[(j + 2) * M + tid];
            float w3 = W1T[(j + 3) * M + tid];
            #pragma unroll
            for (int u = 0; u < UB; ++u) {
                float4 x = *(const float4*)&ps[u][j];
                acc[u] = fmaf(w0, x.x, acc[u]); acc[u] = fmaf(w1, x.y, acc[u]);
                acc[u] = fmaf(w2, x.z, acc[u]); acc[u] = fmaf(w3, x.w, acc[u]);
            }
        }
        for (int j = 0; j < M; j += 4) {
            float w0 = W1T[(M + j + 0) * M + tid];
            float w1 = W1T[(M + j + 1) * M + tid];
            float w2 = W1T[(M + j + 2) * M + tid];
            float w3 = W1T[(M + j + 3) * M + tid];
            #pragma unroll
            for (int u = 0; u < UB; ++u) {
                float4 x = *(const float4*)&pd[u][j];
                acc[u] = fmaf(w0, x.x, acc[u]); acc[u] = fmaf(w1, x.y, acc[u]);
                acc[u] = fmaf(w2, x.z, acc[u]); acc[u] = fmaf(w3, x.w, acc[u]);
            }
        }
        {
            float w0 = W1T[(2 * M + 0) * M + tid];
            float w1 = W1T[(2 * M + 1) * M + tid];
            float w2 = W1T[(2 * M + 2) * M + tid];
            #pragma unroll
            for (int u = 0; u < UB; ++u) {
                acc[u] = fmaf(w0, efs[u][0], acc[u]);
                acc[u] = fmaf(w1, efs[u][1], acc[u]);
                acc[u] = fmaf(w2, efs[u][2], acc[u]);
            }
        }
        #pragma unroll
        for (int u = 0; u < UB; ++u) h1s[u][tid] = fmaxf(acc[u], 0.f);
    }
    __syncthreads();

    // ---- GEMV2: msg = W2 @ h1 + b2 ----
    {
        float acc[UB];
        float bv = b2[tid];
        #pragma unroll
        for (int u = 0; u < UB; ++u) acc[u] = bv;
        for (int j = 0; j < M; j += 4) {
            float w0 = W2T[(j + 0) * M + tid];
            float w1 = W2T[(j + 1) * M + tid];
            float w2 = W2T[(j + 2) * M + tid];
            float w3 = W2T[(j + 3) * M + tid];
            #pragma unroll
            for (int u = 0; u < UB; ++u) {
                float4 x = *(const float4*)&h1s[u][j];
                acc[u] = fmaf(w0, x.x, acc[u]); acc[u] = fmaf(w1, x.y, acc[u]);
                acc[u] = fmaf(w2, x.z, acc[u]); acc[u] = fmaf(w3, x.w, acc[u]);
            }
        }
        #pragma unroll
        for (int u = 0; u < UB; ++u) msg[u][tid] = acc[u];
    }
    __syncthreads();

    // ---- GEMV3: gi = wih@msg + bih ; gh_s = whh@ps + bhh ; gh_d = whh@pd + bhh ----
    float gir[UB], giz[UB], gin[UB], gsr[UB], gsz[UB], gsn[UB], gdr[UB], gdz[UB], gdn[UB];
    {
        float bir = bih[tid], biz = bih[M + tid], bin = bih[2 * M + tid];
        float bhr = bhh[tid], bhz = bhh[M + tid], bhn = bhh[2 * M + tid];
        #pragma unroll
        for (int u = 0; u < UB; ++u) {
            gir[u] = bir; giz[u] = biz; gin[u] = bin;
            gsr[u] = bhr; gsz[u] = bhz; gsn[u] = bhn;
            gdr[u] = bhr; gdz[u] = bhz; gdn[u] = bhn;
        }
        const float* wi = wihT + tid;
        const float* wh = whhT + tid;
        for (int j = 0; j < M; j += 4) {
            float wir0 = wi[(j+0)*G3],         wir1 = wi[(j+1)*G3],         wir2 = wi[(j+2)*G3],         wir3 = wi[(j+3)*G3];
            float wiz0 = wi[(j+0)*G3+M],       wiz1 = wi[(j+1)*G3+M],       wiz2 = wi[(j+2)*G3+M],       wiz3 = wi[(j+3)*G3+M];
            float win0 = wi[(j+0)*G3+2*M],     win1 = wi[(j+1)*G3+2*M],     win2 = wi[(j+2)*G3+2*M],     win3 = wi[(j+3)*G3+2*M];
            float whr0 = wh[(j+0)*G3],         whr1 = wh[(j+1)*G3],         whr2 = wh[(j+2)*G3],         whr3 = wh[(j+3)*G3];
            float whz0 = wh[(j+0)*G3+M],       whz1 = wh[(j+1)*G3+M],       whz2 = wh[(j+2)*G3+M],       whz3 = wh[(j+3)*G3+M];
            float whn0 = wh[(j+0)*G3+2*M],     whn1 = wh[(j+1)*G3+2*M],     whn2 = wh[(j+2)*G3+2*M],     whn3 = wh[(j+3)*G3+2*M];
            #pragma unroll
            for (int u = 0; u < UB; ++u) {
                float4 xm = *(const float4*)&msg[u][j];
                float4 xs = *(const float4*)&ps[u][j];
                float4 xd = *(const float4*)&pd[u][j];
                gir[u] = fmaf(wir3, xm.w, fmaf(wir2, xm.z, fmaf(wir1, xm.y, fmaf(wir0, xm.x, gir[u]))));
                giz[u] = fmaf(wiz3, xm.w, fmaf(wiz2, xm.z, fmaf(wiz1, xm.y, fmaf(wiz0, xm.x, giz[u]))));
                gin[u] = fmaf(win3, xm.w, fmaf(win2, xm.z, fmaf(win1, xm.y, fmaf(win0, xm.x, gin[u]))));
                gsr[u] = fmaf(whr3, xs.w, fmaf(whr2, xs.z, fmaf(whr1, xs.y, fmaf(whr0, xs.x, gsr[u]))));
                gsz[u] = fmaf(whz3, xs.w, fmaf(whz2, xs.z, fmaf(whz1, xs.y, fmaf(whz0, xs.x, gsz[u]))));
                gsn[u] = fmaf(whn3, xs.w, fmaf(whn2, xs.z, fmaf(whn1, xs.y, fmaf(whn0, xs.x, gsn[u]))));
                gdr[u] = fmaf(whr3, xd.w, fmaf(whr2, xd.z, fmaf(whr1, xd.y, fmaf(whr0, xd.x, gdr[u]))));
                gdz[u] = fmaf(whz3, xd.w, fmaf(whz2, xd.z, fmaf(whz1, xd.y, fmaf(whz0, xd.x, gdz[u]))));
                gdn[u] = fmaf(whn3, xd.w, fmaf(whn2, xd.z, fmaf(whn1, xd.y, fmaf(whn0, xd.x, gdn[u]))));
            }
        }
    }

    // ---- gates + scatter (dst wins when s==d, matching ref write order) ----
    #pragma unroll
    for (int u = 0; u < UB; ++u) {
        if (actA[u]) {   // uniform across block
            float irv = gir[u], izv = giz[u], inv = gin[u];
            float rs_ = 1.f / (1.f + expf(-(irv + gsr[u])));
            float zs_ = 1.f / (1.f + expf(-(izv + gsz[u])));
            float ns_ = tanhf(inv + rs_ * gsn[u]);
            float hs  = ps[u][tid];
            float us  = (1.f - zs_) * ns_ + zs_ * hs;
            float rd_ = 1.f / (1.f + expf(-(irv + gdr[u])));
            float zd_ = 1.f / (1.f + expf(-(izv + gdz[u])));
            float ndv = tanhf(inv + rd_ * gdn[u]);
            float hd  = pd[u][tid];
            float ud  = (1.f - zd_) * ndv + zd_ * hd;
            int s = sA[u], d = dA[u];
            if (s != d) mem[(size_t)s * M + tid] = us;
            mem[(size_t)d * M + tid] = ud;
        }
    }
    if (tid < UB && actA[tid]) {
        done_round[blockIdx.x * UB + tid] = r;
        atomicAdd(n_done, 1);
    }
}

// ---------------------------------------------------------------------------
extern "C" void kernel_launch(void* const* d_in, const int* in_sizes, int n_in,
                              void* d_out, int out_size, void* d_ws, size_t ws_size,
                              hipStream_t stream) {
    const int*   src   = (const int*)d_in[0];
    const int*   dst   = (const int*)d_in[1];
    const float* ef    = (const float*)d_in[2];
    const int*   tsi   = (const int*)d_in[3];
    const float* memin = (const float*)d_in[4];
    const float* lu0   = (const float*)d_in[5];
    const float* W1    = (const float*)d_in[6];
    const float* b1    = (const float*)d_in[7];
    const float* W2    = (const float*)d_in[8];
    const float* b2    = (const float*)d_in[9];
    const float* wih   = (const float*)d_in[10];
    const float* whh   = (const float*)d_in[11];
    const float* bih   = (const float*)d_in[12];
    const float* bhh   = (const float*)d_in[13];
    float* mem = (float*)d_out;

    // ws carve (≈2.4 MB)
    float* W1T  = (float*)d_ws;              // 515*256
    float* W2T  = W1T + IN1 * M;             // 256*256
    float* wihT = W2T + M * M;               // 256*768
    float* whhT = wihT + M * G3;             // 256*768
    int* dep_s      = (int*)(whhT + M * G3); // 4096
    int* dep_d      = dep_s + B;
    int* done_round = dep_d + B;
    int* n_done     = done_round + B;

    // output = input memory, then apply updates in place
    hipMemcpyAsync(mem, memin, (size_t)NNODES * M * sizeof(float),
                   hipMemcpyDeviceToDevice, stream);

    tgn_prep_init<<<(M * G3 + 255) / 256, 256, 0, stream>>>(
        W1, W2, wih, whh, W1T, W2T, wihT, whhT, done_round, n_done);
    tgn_prep_deps<<<(B * 8) / 256, 256, 0, stream>>>(src, dst, dep_s, dep_d);

    for (int r = 0; r < NROUNDS; ++r) {
        tgn_round<<<B / UB, 256, 0, stream>>>(
            r, src, dst, ef, tsi, lu0, b1, b2, bih, bhh,
            W1T, W2T, wihT, whhT, dep_s, dep_d, done_round, n_done, mem);
    }
}

// Round 2
// 470.696 us; speedup vs baseline: 1.4980x; 1.4980x over previous
//
#include <hip/hip_runtime.h>
#include <math.h>

#define NNODES 100000
#define B 4096
#define M 256
#define G3 768
#define UB 16
#define ROWP 264
#define NROUNDS 12
#define NOTDONE 0x7fffffff
#define ALPHA 0.1f

typedef __attribute__((ext_vector_type(8))) short short8;
typedef __attribute__((ext_vector_type(4))) short short4v;
typedef __attribute__((ext_vector_type(4))) float f32x4;

__device__ __forceinline__ short bf16rne(float x) {
    union { float f; unsigned u; } v; v.f = x;
    unsigned r = v.u + 0x7fffu + ((v.u >> 16) & 1u);
    return (short)(r >> 16);
}
__device__ __forceinline__ float bf2f(short h) {
    union { unsigned u; float f; } v; v.u = ((unsigned)(unsigned short)h) << 16;
    return v.f;
}
__device__ __forceinline__ void split2(float x, short &hi, short &lo) {
    hi = bf16rne(x);
    lo = bf16rne(x - bf2f(hi));
}

// ---------------------------------------------------------------------------
// Prep: fp32 -> bf16 weight casts (layouts unchanged: [N][K] row-major is
// exactly the MFMA B-operand-friendly layout), init flags.
// ---------------------------------------------------------------------------
__global__ void tgn_prep(const float* __restrict__ W1, const float* __restrict__ W2,
                         const float* __restrict__ wih, const float* __restrict__ whh,
                         short* __restrict__ W1h, short* __restrict__ W2h,
                         short* __restrict__ wihH, short* __restrict__ whhH,
                         int* __restrict__ done_round, int* __restrict__ n_done)
{
    int t = blockIdx.x * 256 + threadIdx.x;
    if (t < 256 * 512) { int n = t >> 9, k = t & 511; W1h[t] = bf16rne(W1[n * 515 + k]); }
    if (t < 256 * 256) { W2h[t] = bf16rne(W2[t]); }
    if (t < 768 * 256) { wihH[t] = bf16rne(wih[t]); whhH[t] = bf16rne(whh[t]); }
    if (t < B) done_round[t] = NOTDONE;
    if (t == 0) *n_done = 0;
}

// ---------------------------------------------------------------------------
// Deps: dep_s[i] = max j<i with s_j==s_i || d_j==s_i (else -1); dep_d likewise.
// ---------------------------------------------------------------------------
__global__ void tgn_prep_deps(const int* __restrict__ src, const int* __restrict__ dst,
                              int* __restrict__ dep_s, int* __restrict__ dep_d)
{
    __shared__ int sL[B];
    __shared__ int dL[B];
    __shared__ int rs[256], rd[256];
    int tid = threadIdx.x;
    for (int idx = tid; idx < B; idx += 256) { sL[idx] = src[idx]; dL[idx] = dst[idx]; }
    __syncthreads();

    int gw = blockIdx.x * 256 + tid;
    int i = gw >> 3;
    int w = gw & 7;
    int vs = sL[i], vd = dL[i];
    int lo = w * 512;
    int hi = (w + 1) * 512; if (hi > i) hi = i;
    int bs = -1, bd = -1;
    for (int j = hi - 1; j >= lo; --j) {
        int sj = sL[j], dj = dL[j];
        if (bs < 0 && (sj == vs || dj == vs)) bs = j;
        if (bd < 0 && (sj == vd || dj == vd)) bd = j;
        if (bs >= 0 && bd >= 0) break;
    }
    rs[tid] = bs; rd[tid] = bd;
    __syncthreads();
    if (w == 0) {
        int ms = -1, md = -1;
        #pragma unroll
        for (int q = 0; q < 8; ++q) { ms = max(ms, rs[tid + q]); md = max(md, rd[tid + q]); }
        dep_s[i] = ms; dep_d[i] = md;
    }
}

// ---------------------------------------------------------------------------
// One round: block b owns steps [16b, 16b+16). MFMA 16x16x32 bf16 with
// hi/lo-split activations. A[m=lane&15][k=quad*8+j]; B[k][n=lane&15] from
// row-major [N][K] weights; D: row m = quad*4+reg, col n = lane&15.
// ---------------------------------------------------------------------------
__global__ __launch_bounds__(256) void tgn_round(
    int r,
    const int* __restrict__ src, const int* __restrict__ dst,
    const float* __restrict__ ef, const int* __restrict__ tsi,
    const float* __restrict__ lu0,
    const float* __restrict__ W1g,
    const float* __restrict__ b1, const float* __restrict__ b2,
    const float* __restrict__ bih, const float* __restrict__ bhh,
    const short* __restrict__ W1h, const short* __restrict__ W2h,
    const short* __restrict__ wihH, const short* __restrict__ whhH,
    const int* __restrict__ dep_s, const int* __restrict__ dep_d,
    int* __restrict__ done_round, int* __restrict__ n_done,
    float* __restrict__ mem)
{
    __shared__ __align__(16) short psH[UB * ROWP];
    __shared__ __align__(16) short psL[UB * ROWP];
    __shared__ __align__(16) short pdH[UB * ROWP];
    __shared__ __align__(16) short pdL[UB * ROWP];
    __shared__ __align__(16) short xH[UB * ROWP];   // h1 then msg
    __shared__ __align__(16) short xL[UB * ROWP];
    __shared__ float efs[UB][3];
    __shared__ float decS[UB], decD[UB];
    __shared__ int sA[UB], dA[UB], actA[UB];
    __shared__ int nd_sh;

    int tid = threadIdx.x;
    if (tid == 0) nd_sh = *n_done;
    __syncthreads();
    if (nd_sh >= B) return;          // uniform early exit

    if (tid < UB) {
        int i = blockIdx.x * UB + tid;
        bool ready = false;
        int a = dep_s[i], bb = dep_d[i];
        if (done_round[i] == NOTDONE) {
            ready = (a < 0 || done_round[a] < r) && (bb < 0 || done_round[bb] < r);
        }
        int s = 0, d = 0; float dcs = 0.f, dcd = 0.f, e0 = 0.f, e1 = 0.f, e2 = 0.f;
        if (ready) {
            s = src[i]; d = dst[i];
            float t = (float)tsi[i];
            float lus = (a  >= 0) ? (float)tsi[a]  : lu0[s];
            float lud = (bb >= 0) ? (float)tsi[bb] : lu0[d];
            dcs = expf(-ALPHA * fmaxf(t - lus, 0.f));
            dcd = expf(-ALPHA * fmaxf(t - lud, 0.f));
            e0 = ef[3 * i]; e1 = ef[3 * i + 1]; e2 = ef[3 * i + 2];
        }
        sA[tid] = s; dA[tid] = d; actA[tid] = ready ? 1 : 0;
        decS[tid] = dcs; decD[tid] = dcd;
        efs[tid][0] = e0; efs[tid][1] = e1; efs[tid][2] = e2;
    }
    __syncthreads();
    int anyact = 0;
    #pragma unroll
    for (int u = 0; u < UB; ++u) anyact += actA[u];
    if (anyact == 0) return;         // uniform

    // ---- stage decayed states as hi/lo bf16 (and exact-ish fp32 = hi+lo) ----
    #pragma unroll
    for (int i = 0; i < 4; ++i) {
        int e4 = tid + i * 256;          // 1024 float4 rows-worth
        int u  = e4 >> 6;                // step
        int c4 = e4 & 63;                // float4 index in row
        float4 vs = *((const float4*)(mem + (size_t)sA[u] * M) + c4);
        float4 vd = *((const float4*)(mem + (size_t)dA[u] * M) + c4);
        float ds_ = decS[u], dd_ = decD[u];
        short h0,h1_,h2,h3,l0,l1,l2,l3;
        split2(vs.x * ds_, h0, l0); split2(vs.y * ds_, h1_, l1);
        split2(vs.z * ds_, h2, l2); split2(vs.w * ds_, h3, l3);
        short4v hv = {h0, h1_, h2, h3}, lv = {l0, l1, l2, l3};
        *(short4v*)&psH[u * ROWP + c4 * 4] = hv;
        *(short4v*)&psL[u * ROWP + c4 * 4] = lv;
        split2(vd.x * dd_, h0, l0); split2(vd.y * dd_, h1_, l1);
        split2(vd.z * dd_, h2, l2); split2(vd.w * dd_, h3, l3);
        short4v hv2 = {h0, h1_, h2, h3}, lv2 = {l0, l1, l2, l3};
        *(short4v*)&pdH[u * ROWP + c4 * 4] = hv2;
        *(short4v*)&pdL[u * ROWP + c4 * 4] = lv2;
    }
    __syncthreads();

    int wav = tid >> 6, lane = tid & 63, ln = lane & 15, quad = lane >> 4;

    // ---- GEMM1: h1 = relu([ps pd] @ W1[:, :512]^T + ef @ W1[:,512:]^T + b1) ----
    {
        f32x4 acc[4] = { {0,0,0,0}, {0,0,0,0}, {0,0,0,0}, {0,0,0,0} };
        for (int kb = 0; kb < 16; ++kb) {
            const short* aHp = (kb < 8) ? psH : pdH;
            const short* aLp = (kb < 8) ? psL : pdL;
            int kk = (kb & 7) * 32 + quad * 8;
            short8 ah = *(const short8*)&aHp[ln * ROWP + kk];
            short8 al = *(const short8*)&aLp[ln * ROWP + kk];
            int kg = kb * 32 + quad * 8;
            #pragma unroll
            for (int t = 0; t < 4; ++t) {
                int n = wav * 64 + t * 16 + ln;
                short8 b = *(const short8*)(W1h + (size_t)n * 512 + kg);
                acc[t] = __builtin_amdgcn_mfma_f32_16x16x32_bf16(ah, b, acc[t], 0, 0, 0);
                acc[t] = __builtin_amdgcn_mfma_f32_16x16x32_bf16(al, b, acc[t], 0, 0, 0);
            }
        }
        #pragma unroll
        for (int t = 0; t < 4; ++t) {
            int n = wav * 64 + t * 16 + ln;
            float bv = b1[n];
            float w0 = W1g[n * 515 + 512], w1 = W1g[n * 515 + 513], w2 = W1g[n * 515 + 514];
            #pragma unroll
            for (int reg = 0; reg < 4; ++reg) {
                int m = quad * 4 + reg;
                float v = acc[t][reg] + bv + w0 * efs[m][0] + w1 * efs[m][1] + w2 * efs[m][2];
                v = fmaxf(v, 0.f);
                short hi, lo; split2(v, hi, lo);
                xH[m * ROWP + n] = hi; xL[m * ROWP + n] = lo;
            }
        }
    }
    __syncthreads();

    // ---- GEMM2: msg = h1 @ W2^T + b2 (result overwrites x after barrier) ----
    {
        f32x4 acc[4] = { {0,0,0,0}, {0,0,0,0}, {0,0,0,0}, {0,0,0,0} };
        for (int kb = 0; kb < 8; ++kb) {
            int kk = kb * 32 + quad * 8;
            short8 ah = *(const short8*)&xH[ln * ROWP + kk];
            short8 al = *(const short8*)&xL[ln * ROWP + kk];
            #pragma unroll
            for (int t = 0; t < 4; ++t) {
                int n = wav * 64 + t * 16 + ln;
                short8 b = *(const short8*)(W2h + (size_t)n * 256 + kk);
                acc[t] = __builtin_amdgcn_mfma_f32_16x16x32_bf16(ah, b, acc[t], 0, 0, 0);
                acc[t] = __builtin_amdgcn_mfma_f32_16x16x32_bf16(al, b, acc[t], 0, 0, 0);
            }
        }
        __syncthreads();   // all h1 reads complete before overwrite
        #pragma unroll
        for (int t = 0; t < 4; ++t) {
            int n = wav * 64 + t * 16 + ln;
            float bv = b2[n];
            #pragma unroll
            for (int reg = 0; reg < 4; ++reg) {
                int m = quad * 4 + reg;
                float v = acc[t][reg] + bv;
                short hi, lo; split2(v, hi, lo);
                xH[m * ROWP + n] = hi; xL[m * ROWP + n] = lo;
            }
        }
    }
    __syncthreads();

    // ---- GEMM3 + GRU epilogue: 9 gate tiles per n0-chunk, all in-register ----
    for (int t = 0; t < 4; ++t) {
        int n0 = wav * 64 + t * 16;
        f32x4 aIR = {0,0,0,0}, aIZ = {0,0,0,0}, aIN = {0,0,0,0};
        f32x4 aSR = {0,0,0,0}, aSZ = {0,0,0,0}, aSN = {0,0,0,0};
        f32x4 aDR = {0,0,0,0}, aDZ = {0,0,0,0}, aDN = {0,0,0,0};
        for (int kb = 0; kb < 8; ++kb) {
            int kk = kb * 32 + quad * 8;
            short8 xmh = *(const short8*)&xH[ln * ROWP + kk];
            short8 xml = *(const short8*)&xL[ln * ROWP + kk];
            short8 xsh = *(const short8*)&psH[ln * ROWP + kk];
            short8 xsl = *(const short8*)&psL[ln * ROWP + kk];
            short8 xdh = *(const short8*)&pdH[ln * ROWP + kk];
            short8 xdl = *(const short8*)&pdL[ln * ROWP + kk];
            int nr = n0 + ln;
            short8 bir = *(const short8*)(wihH + (size_t)nr * 256 + kk);
            short8 biz = *(const short8*)(wihH + (size_t)(nr + 256) * 256 + kk);
            short8 bin = *(const short8*)(wihH + (size_t)(nr + 512) * 256 + kk);
            short8 bhr = *(const short8*)(whhH + (size_t)nr * 256 + kk);
            short8 bhz = *(const short8*)(whhH + (size_t)(nr + 256) * 256 + kk);
            short8 bhn = *(const short8*)(whhH + (size_t)(nr + 512) * 256 + kk);
            aIR = __builtin_amdgcn_mfma_f32_16x16x32_bf16(xmh, bir, aIR, 0, 0, 0);
            aIR = __builtin_amdgcn_mfma_f32_16x16x32_bf16(xml, bir, aIR, 0, 0, 0);
            aIZ = __builtin_amdgcn_mfma_f32_16x16x32_bf16(xmh, biz, aIZ, 0, 0, 0);
            aIZ = __builtin_amdgcn_mfma_f32_16x16x32_bf16(xml, biz, aIZ, 0, 0, 0);
            aIN = __builtin_amdgcn_mfma_f32_16x16x32_bf16(xmh, bin, aIN, 0, 0, 0);
            aIN = __builtin_amdgcn_mfma_f32_16x16x32_bf16(xml, bin, aIN, 0, 0, 0);
            aSR = __builtin_amdgcn_mfma_f32_16x16x32_bf16(xsh, bhr, aSR, 0, 0, 0);
            aSR = __builtin_amdgcn_mfma_f32_16x16x32_bf16(xsl, bhr, aSR, 0, 0, 0);
            aSZ = __builtin_amdgcn_mfma_f32_16x16x32_bf16(xsh, bhz, aSZ, 0, 0, 0);
            aSZ = __builtin_amdgcn_mfma_f32_16x16x32_bf16(xsl, bhz, aSZ, 0, 0, 0);
            aSN = __builtin_amdgcn_mfma_f32_16x16x32_bf16(xsh, bhn, aSN, 0, 0, 0);
            aSN = __builtin_amdgcn_mfma_f32_16x16x32_bf16(xsl, bhn, aSN, 0, 0, 0);
            aDR = __builtin_amdgcn_mfma_f32_16x16x32_bf16(xdh, bhr, aDR, 0, 0, 0);
            aDR = __builtin_amdgcn_mfma_f32_16x16x32_bf16(xdl, bhr, aDR, 0, 0, 0);
            aDZ = __builtin_amdgcn_mfma_f32_16x16x32_bf16(xdh, bhz, aDZ, 0, 0, 0);
            aDZ = __builtin_amdgcn_mfma_f32_16x16x32_bf16(xdl, bhz, aDZ, 0, 0, 0);
            aDN = __builtin_amdgcn_mfma_f32_16x16x32_bf16(xdh, bhn, aDN, 0, 0, 0);
            aDN = __builtin_amdgcn_mfma_f32_16x16x32_bf16(xdl, bhn, aDN, 0, 0, 0);
        }
        int n = n0 + ln;
        float bir_ = bih[n], biz_ = bih[M + n], bin_ = bih[2 * M + n];
        float bhr_ = bhh[n], bhz_ = bhh[M + n], bhn_ = bhh[2 * M + n];
        #pragma unroll
        for (int reg = 0; reg < 4; ++reg) {
            int m = quad * 4 + reg;
            if (actA[m]) {
                float gir = aIR[reg] + bir_;
                float giz = aIZ[reg] + biz_;
                float gin = aIN[reg] + bin_;
                float hs = bf2f(psH[m * ROWP + n]) + bf2f(psL[m * ROWP + n]);
                float hd = bf2f(pdH[m * ROWP + n]) + bf2f(pdL[m * ROWP + n]);
                float rs_ = 1.f / (1.f + expf(-(gir + aSR[reg] + bhr_)));
                float zs_ = 1.f / (1.f + expf(-(giz + aSZ[reg] + bhz_)));
                float ns_ = tanhf(gin + rs_ * (aSN[reg] + bhn_));
                float us  = (1.f - zs_) * ns_ + zs_ * hs;
                float rd_ = 1.f / (1.f + expf(-(gir + aDR[reg] + bhr_)));
                float zd_ = 1.f / (1.f + expf(-(giz + aDZ[reg] + bhz_)));
                float nd_ = tanhf(gin + rd_ * (aDN[reg] + bhn_));
                float ud  = (1.f - zd_) * nd_ + zd_ * hd;
                int s = sA[m], d = dA[m];
                if (s != d) mem[(size_t)s * M + n] = us;
                mem[(size_t)d * M + n] = ud;
            }
        }
    }

    if (tid < UB && actA[tid]) {
        done_round[blockIdx.x * UB + tid] = r;
        atomicAdd(n_done, 1);
    }
}

// ---------------------------------------------------------------------------
extern "C" void kernel_launch(void* const* d_in, const int* in_sizes, int n_in,
                              void* d_out, int out_size, void* d_ws, size_t ws_size,
                              hipStream_t stream) {
    const int*   src   = (const int*)d_in[0];
    const int*   dst   = (const int*)d_in[1];
    const float* ef    = (const float*)d_in[2];
    const int*   tsi   = (const int*)d_in[3];
    const float* memin = (const float*)d_in[4];
    const float* lu0   = (const float*)d_in[5];
    const float* W1    = (const float*)d_in[6];
    const float* b1    = (const float*)d_in[7];
    const float* W2    = (const float*)d_in[8];
    const float* b2    = (const float*)d_in[9];
    const float* wih   = (const float*)d_in[10];
    const float* whh   = (const float*)d_in[11];
    const float* bih   = (const float*)d_in[12];
    const float* bhh   = (const float*)d_in[13];
    float* mem = (float*)d_out;

    // ws carve (~1.23 MB)
    short* W1h  = (short*)d_ws;              // 256*512
    short* W2h  = W1h + 256 * 512;           // 256*256
    short* wihH = W2h + 256 * 256;           // 768*256
    short* whhH = wihH + 768 * 256;          // 768*256
    int* dep_s      = (int*)(whhH + 768 * 256);
    int* dep_d      = dep_s + B;
    int* done_round = dep_d + B;
    int* n_done     = done_round + B;

    hipMemcpyAsync(mem, memin, (size_t)NNODES * M * sizeof(float),
                   hipMemcpyDeviceToDevice, stream);

    tgn_prep<<<768, 256, 0, stream>>>(W1, W2, wih, whh, W1h, W2h, wihH, whhH,
                                      done_round, n_done);
    tgn_prep_deps<<<(B * 8) / 256, 256, 0, stream>>>(src, dst, dep_s, dep_d);

    for (int r = 0; r < NROUNDS; ++r) {
        tgn_round<<<B / UB, 256, 0, stream>>>(
            r, src, dst, ef, tsi, lu0, W1, b1, b2, bih, bhh,
            W1h, W2h, wihH, whhH, dep_s, dep_d, done_round, n_done, mem);
    }
}